// Round 2
// baseline (24068.716 us; speedup 1.0000x reference)
//
#include <hip/hip_runtime.h>
#include <math.h>

#define B_  16
#define D_  2048
#define T_  100
#define N0_ 4096
#define N1_ 4096
#define N2_ 2048
#define NC_ 10

// ---------------- rates = sigmoid(x @ W_enc + b_enc) ----------------
__global__ __launch_bounds__(256) void rates_kernel(
    const float* __restrict__ x, const float* __restrict__ W_enc,
    const float* __restrict__ b_enc, float* __restrict__ rates)
{
    int tid = blockIdx.x * 256 + threadIdx.x;      // 65536 = B*N0
    int b = tid >> 12, i = tid & (N0_ - 1);
    const float* xr = x + b * D_;
    float acc = 0.f;
    for (int d = 0; d < D_; ++d)
        acc = fmaf(xr[d], W_enc[(size_t)d * N0_ + i], acc);
    float z = __fadd_rn(acc, b_enc[i]);
    rates[tid] = 1.0f / (1.0f + expf(-z));         // (B, N0)
}

// ---- layer-0 LIF over all T (independent of weights): s0, p0 in (T,N0,B) ----
__global__ __launch_bounds__(256) void layer0_kernel(
    const float* __restrict__ u, const float* __restrict__ rates,
    float* __restrict__ s0_all, float* __restrict__ p0_all)
{
    int tid = blockIdx.x * 256 + threadIdx.x;      // 65536
    int b = tid & (B_ - 1), i = tid >> 4;
    float rate = rates[b * N0_ + i];
    const float* ub = u + (size_t)b * T_ * N0_ + i;  // u is (B,T,N0)
    float V = 0.f, refr = 0.f, p0 = 0.f;
    for (int t = 0; t < T_; ++t) {
        float uv = ub[(size_t)t * N0_];
        float s_in = (uv < rate) ? 1.0f : 0.0f;
        V = __fadd_rn(__fmul_rn(0.9f, V), s_in);
        bool spk = (V > 1.0f) && (refr <= 0.0f);
        float s = spk ? 1.0f : 0.0f;
        V = spk ? 0.0f : V;
        refr = spk ? 2.0f : fmaxf(refr - 1.0f, 0.0f);
        p0 = __fadd_rn(__fmul_rn(0.95f, p0), s);   // trace after spike, per reference
        size_t idx = ((size_t)t * N0_ + i) * B_ + b;
        s0_all[idx] = s;
        p0_all[idx] = p0;
    }
}

// dot16 in fixed b-ascending order
__device__ __forceinline__ float dot16(const float4 r[4], const float* v) {
    float t = 0.f;
    t = fmaf(r[0].x, v[0], t);  t = fmaf(r[0].y, v[1], t);
    t = fmaf(r[0].z, v[2], t);  t = fmaf(r[0].w, v[3], t);
    t = fmaf(r[1].x, v[4], t);  t = fmaf(r[1].y, v[5], t);
    t = fmaf(r[1].z, v[6], t);  t = fmaf(r[1].w, v[7], t);
    t = fmaf(r[2].x, v[8], t);  t = fmaf(r[2].y, v[9], t);
    t = fmaf(r[2].z, v[10], t); t = fmaf(r[2].w, v[11], t);
    t = fmaf(r[3].x, v[12], t); t = fmaf(r[3].y, v[13], t);
    t = fmaf(r[3].z, v[14], t); t = fmaf(r[3].w, v[15], t);
    return t;
}
__device__ __forceinline__ void acc16(float* acc, const float4 r[4], float w) {
    acc[0]  = fmaf(r[0].x, w, acc[0]);  acc[1]  = fmaf(r[0].y, w, acc[1]);
    acc[2]  = fmaf(r[0].z, w, acc[2]);  acc[3]  = fmaf(r[0].w, w, acc[3]);
    acc[4]  = fmaf(r[1].x, w, acc[4]);  acc[5]  = fmaf(r[1].y, w, acc[5]);
    acc[6]  = fmaf(r[1].z, w, acc[6]);  acc[7]  = fmaf(r[1].w, w, acc[7]);
    acc[8]  = fmaf(r[2].x, w, acc[8]);  acc[9]  = fmaf(r[2].y, w, acc[9]);
    acc[10] = fmaf(r[2].z, w, acc[10]); acc[11] = fmaf(r[2].w, w, acc[11]);
    acc[12] = fmaf(r[3].x, w, acc[12]); acc[13] = fmaf(r[3].y, w, acc[13]);
    acc[14] = fmaf(r[3].z, w, acc[14]); acc[15] = fmaf(r[3].w, w, acc[15]);
}
__device__ __forceinline__ void ld_lds4(float4 r[4], const float4* p) {
    r[0] = p[0]; r[1] = p[1]; r[2] = p[2]; r[3] = p[3];
}

// ---- fused: apply dWa(t-1)+clip, then partial y1(t) = s0(t) @ Wa ----
// grid 1024: 16 j-tiles(256) x 64 i-chunks(64 rows).
// Row data (s0t / s0p / p0p) staged in LDS once per block (12 KB) -> inner
// loop is pure ds_read broadcast + weight stream. Weight stream is 8-row
// double-buffered so ~900 cycles of L3 latency are covered.
__global__ __launch_bounds__(256, 4) void ka_kernel(
    float* __restrict__ Wa,            // (N0, N1) in-place
    const float* __restrict__ s0_all,  // (T, N0, B)
    const float* __restrict__ p0_all,  // (T, N0, B)
    const float* __restrict__ s1_bj,   // (2, B, N1)
    const float* __restrict__ q0_bj,   // (2, B, N1)
    float* __restrict__ pa, int t, int store_w)
{
    const int jt = blockIdx.x >> 6;         // 0..15
    const int chunk = blockIdx.x & 63;      // 0..63
    const int j0 = jt * 256 + threadIdx.x;
    const int i0 = chunk * 64;
    const int prev = 1 - (t & 1);

    __shared__ float4 ls0t[256];   // [row][quad] = [64][4]
    __shared__ float4 ls0p[256];
    __shared__ float4 lp0p[256];

    const float* s0t = s0_all + (size_t)t * N0_ * B_;
    {
        const int r = threadIdx.x >> 2, q = threadIdx.x & 3;
        ls0t[threadIdx.x] = ((const float4*)(s0t + (size_t)(i0 + r) * B_))[q];
        if (t > 0) {
            const float* s0p = s0_all + (size_t)(t - 1) * N0_ * B_;
            const float* p0p = p0_all + (size_t)(t - 1) * N0_ * B_;
            ls0p[threadIdx.x] = ((const float4*)(s0p + (size_t)(i0 + r) * B_))[q];
            lp0p[threadIdx.x] = ((const float4*)(p0p + (size_t)(i0 + r) * B_))[q];
        }
    }
    __syncthreads();

    float acc0[B_];
    #pragma unroll
    for (int b = 0; b < B_; ++b) acc0[b] = 0.f;

    if (t > 0) {
        float s1v0[B_], q0v0[B_];
        #pragma unroll
        for (int b = 0; b < B_; ++b) {
            s1v0[b] = s1_bj[((size_t)prev * B_ + b) * N1_ + j0];
            q0v0[b] = q0_bj[((size_t)prev * B_ + b) * N1_ + j0];
        }
        float* wp = Wa + (size_t)i0 * N1_ + j0;
        float wbuf[8], wnext[8];
        #pragma unroll
        for (int g = 0; g < 8; ++g) wbuf[g] = wp[(size_t)g * N1_];
        for (int grp = 0; grp < 8; ++grp) {
            const int base = grp * 8;
            if (grp < 7) {
                #pragma unroll
                for (int g = 0; g < 8; ++g)
                    wnext[g] = wp[(size_t)(base + 8 + g) * N1_];
            }
            #pragma unroll
            for (int g = 0; g < 8; ++g) {
                const int ii = base + g;
                float4 p0r[4], s0r[4], s0tr[4];
                ld_lds4(p0r,  &lp0p[ii << 2]);
                ld_lds4(s0r,  &ls0p[ii << 2]);
                ld_lds4(s0tr, &ls0t[ii << 2]);
                float t1a = dot16(p0r, s1v0), t2a = dot16(s0r, q0v0);
                float wn0 = __fadd_rn(wbuf[g], __fmul_rn(0.01f, __fsub_rn(t1a, t2a)));
                wn0 = fminf(fmaxf(wn0, -1.0f), 1.0f);
                if (store_w)
                    wp[(size_t)ii * N1_] = wn0;
                acc16(acc0, s0tr, wn0);
            }
            #pragma unroll
            for (int g = 0; g < 8; ++g) wbuf[g] = wnext[g];
        }
    } else {
        #pragma unroll 2
        for (int ii = 0; ii < 64; ++ii) {
            float4 s0tr[4];
            ld_lds4(s0tr, &ls0t[ii << 2]);
            float w0 = Wa[(size_t)(i0 + ii) * N1_ + j0];
            acc16(acc0, s0tr, w0);
        }
    }
    #pragma unroll
    for (int b = 0; b < B_; ++b)
        pa[((size_t)chunk * B_ + b) * N1_ + j0] = acc0[b];
}

// ---- LIF layer 1: reduce pa (fixed order, 64 chunks), V1/r1, s1, q0, p1 ----
__global__ __launch_bounds__(256) void lif1_kernel(
    const float* __restrict__ pa, float* __restrict__ V1, float* __restrict__ r1,
    float* __restrict__ s1_bj, float* __restrict__ s1_jb,
    float* __restrict__ q0_bj, float* __restrict__ p1_jb, int t)
{
    int tid = blockIdx.x * 256 + threadIdx.x;      // 65536 = B*N1
    int b = tid >> 12, j = tid & (N1_ - 1);
    float y = 0.f;
    #pragma unroll 16
    for (int c = 0; c < 64; ++c) y += pa[((size_t)c * B_ + b) * N1_ + j];
    float V = __fadd_rn(__fmul_rn(0.9f, V1[tid]), y);
    float rr = r1[tid];
    bool spk = (V > 1.0f) && (rr <= 0.0f);
    float s = spk ? 1.0f : 0.0f;
    V1[tid] = spk ? 0.0f : V;
    r1[tid] = spk ? 2.0f : fmaxf(rr - 1.0f, 0.0f);
    int cur = t & 1, prev = 1 - cur;
    s1_bj[(size_t)cur * B_ * N1_ + tid] = s;
    s1_jb[(size_t)cur * B_ * N1_ + (size_t)j * B_ + b] = s;
    float q0 = __fadd_rn(__fmul_rn(0.95f, q0_bj[(size_t)prev * B_ * N1_ + tid]), s);
    q0_bj[(size_t)cur * B_ * N1_ + tid] = q0;
    float p1 = __fadd_rn(__fmul_rn(0.95f, p1_jb[(size_t)prev * B_ * N1_ + (size_t)j * B_ + b]), s);
    p1_jb[(size_t)cur * B_ * N1_ + (size_t)j * B_ + b] = p1;
}

// ---- fused: apply dWb(t-1)+clip, then partial y2(t) = s1(t) @ Wb ----
// grid 1024: 8 k-tiles(256) x 128 j-chunks(32 rows). LDS-staged rows (6 KB),
// 8-row double-buffered weight stream.
__global__ __launch_bounds__(256, 4) void kb_kernel(
    float* __restrict__ Wb,            // (N1, N2) in-place
    const float* __restrict__ s1_jb,   // (2, N1, B)
    const float* __restrict__ p1_jb,   // (2, N1, B)
    const float* __restrict__ s2_bk,   // (2, B, N2)
    const float* __restrict__ q1_bk,   // (2, B, N2)
    float* __restrict__ pb, int t, int store_w)
{
    const int kt = blockIdx.x >> 7;         // 0..7
    const int chunk = blockIdx.x & 127;     // 0..127
    const int k0 = kt * 256 + threadIdx.x;
    const int r0 = chunk * 32;
    const int cur = t & 1, prev = 1 - cur;

    __shared__ float4 ls1c[128];   // [row][quad] = [32][4]
    __shared__ float4 ls1p[128];
    __shared__ float4 lp1p[128];

    const float* s1c = s1_jb + (size_t)cur * N1_ * B_;
    {
        if (threadIdx.x < 128) {
            const int r = threadIdx.x >> 2, q = threadIdx.x & 3;
            ls1c[threadIdx.x] = ((const float4*)(s1c + (size_t)(r0 + r) * B_))[q];
        } else if (t > 0) {
            const int tt = threadIdx.x - 128;
            const int r = tt >> 2, q = tt & 3;
            const float* s1p = s1_jb + (size_t)prev * N1_ * B_;
            const float* p1p = p1_jb + (size_t)prev * N1_ * B_;
            ls1p[tt] = ((const float4*)(s1p + (size_t)(r0 + r) * B_))[q];
            lp1p[tt] = ((const float4*)(p1p + (size_t)(r0 + r) * B_))[q];
        }
    }
    __syncthreads();

    float acc0[B_];
    #pragma unroll
    for (int b = 0; b < B_; ++b) acc0[b] = 0.f;

    if (t > 0) {
        float s2v0[B_], q1v0[B_];
        #pragma unroll
        for (int b = 0; b < B_; ++b) {
            s2v0[b] = s2_bk[((size_t)prev * B_ + b) * N2_ + k0];
            q1v0[b] = q1_bk[((size_t)prev * B_ + b) * N2_ + k0];
        }
        float* wp = Wb + (size_t)r0 * N2_ + k0;
        float wbuf[8], wnext[8];
        #pragma unroll
        for (int g = 0; g < 8; ++g) wbuf[g] = wp[(size_t)g * N2_];
        for (int grp = 0; grp < 4; ++grp) {
            const int base = grp * 8;
            if (grp < 3) {
                #pragma unroll
                for (int g = 0; g < 8; ++g)
                    wnext[g] = wp[(size_t)(base + 8 + g) * N2_];
            }
            #pragma unroll
            for (int g = 0; g < 8; ++g) {
                const int jj = base + g;
                float4 p1r[4], s1pr[4], s1cr[4];
                ld_lds4(p1r,  &lp1p[jj << 2]);
                ld_lds4(s1pr, &ls1p[jj << 2]);
                ld_lds4(s1cr, &ls1c[jj << 2]);
                float t1a = dot16(p1r, s2v0), t2a = dot16(s1pr, q1v0);
                float wn0 = __fadd_rn(wbuf[g], __fmul_rn(0.01f, __fsub_rn(t1a, t2a)));
                wn0 = fminf(fmaxf(wn0, -1.0f), 1.0f);
                if (store_w)
                    wp[(size_t)jj * N2_] = wn0;
                acc16(acc0, s1cr, wn0);
            }
            #pragma unroll
            for (int g = 0; g < 8; ++g) wbuf[g] = wnext[g];
        }
    } else {
        #pragma unroll 2
        for (int jj = 0; jj < 32; ++jj) {
            float4 s1cr[4];
            ld_lds4(s1cr, &ls1c[jj << 2]);
            float w0 = Wb[(size_t)(r0 + jj) * N2_ + k0];
            acc16(acc0, s1cr, w0);
        }
    }
    #pragma unroll
    for (int b = 0; b < B_; ++b)
        pb[((size_t)chunk * B_ + b) * N2_ + k0] = acc0[b];
}

// ---- LIF layer 2: reduce pb (128 chunks), V2/r2, s2, q1, spike counts ----
__global__ __launch_bounds__(256) void lif2_kernel(
    const float* __restrict__ pb, float* __restrict__ V2, float* __restrict__ r2,
    float* __restrict__ s2_bk, float* __restrict__ q1_bk,
    float* __restrict__ counts, int t)
{
    int tid = blockIdx.x * 256 + threadIdx.x;      // 32768 = B*N2
    int b = tid >> 11, k = tid & (N2_ - 1);
    float y = 0.f;
    #pragma unroll 16
    for (int c = 0; c < 128; ++c) y += pb[((size_t)c * B_ + b) * N2_ + k];
    float V = __fadd_rn(__fmul_rn(0.9f, V2[tid]), y);
    float rr = r2[tid];
    bool spk = (V > 1.0f) && (rr <= 0.0f);
    float s = spk ? 1.0f : 0.0f;
    V2[tid] = spk ? 0.0f : V;
    r2[tid] = spk ? 2.0f : fmaxf(rr - 1.0f, 0.0f);
    int cur = t & 1, prev = 1 - cur;
    s2_bk[(size_t)cur * B_ * N2_ + tid] = s;
    float q1 = __fadd_rn(__fmul_rn(0.95f, q1_bk[(size_t)prev * B_ * N2_ + tid]), s);
    q1_bk[(size_t)cur * B_ * N2_ + tid] = q1;
    counts[tid] = counts[tid] + s;
}

// ---- decode: out = counts @ W_dec + b_dec ----
__global__ __launch_bounds__(256) void decode_kernel(
    const float* __restrict__ counts, const float* __restrict__ W_dec,
    const float* __restrict__ b_dec, float* __restrict__ out)
{
    int tid = threadIdx.x;
    if (tid < B_ * NC_) {
        int b = tid / NC_, c = tid % NC_;
        float a = 0.f;
        for (int k = 0; k < N2_; ++k)
            a = fmaf(counts[(size_t)b * N2_ + k], W_dec[(size_t)k * NC_ + c], a);
        out[tid] = __fadd_rn(a, b_dec[c]);
    }
}

extern "C" void kernel_launch(void* const* d_in, const int* in_sizes, int n_in,
                              void* d_out, int out_size, void* d_ws, size_t ws_size,
                              hipStream_t stream) {
    const float* x     = (const float*)d_in[0];
    const float* u     = (const float*)d_in[1];
    const float* W_enc = (const float*)d_in[2];
    const float* b_enc = (const float*)d_in[3];
    float* Wa          = (float*)d_in[4];   // updated in place; harness restores before every timed launch
    float* Wb          = (float*)d_in[5];
    const float* W_dec = (const float*)d_in[6];
    const float* b_dec = (const float*)d_in[7];
    float* out         = (float*)d_out;

    float* ws = (float*)d_ws;
    size_t off = 0;
    float* rates  = ws + off; off += (size_t)B_ * N0_;
    float* s0_all = ws + off; off += (size_t)T_ * N0_ * B_;
    float* p0_all = ws + off; off += (size_t)T_ * N0_ * B_;
    float* s1_bj  = ws + off; off += 2 * (size_t)B_ * N1_;
    float* s1_jb  = ws + off; off += 2 * (size_t)B_ * N1_;
    float* pa     = ws + off; off += 64 * (size_t)B_ * N1_;
    float* pb     = ws + off; off += 128 * (size_t)B_ * N2_;
    float* zblock = ws + off;                       // everything below is zero-init state
    float* q0_bj  = ws + off; off += 2 * (size_t)B_ * N1_;
    float* p1_jb  = ws + off; off += 2 * (size_t)B_ * N1_;
    float* q1_bk  = ws + off; off += 2 * (size_t)B_ * N2_;
    float* s2_bk  = ws + off; off += 2 * (size_t)B_ * N2_;
    float* V1     = ws + off; off += (size_t)B_ * N1_;
    float* r1     = ws + off; off += (size_t)B_ * N1_;
    float* V2     = ws + off; off += (size_t)B_ * N2_;
    float* r2     = ws + off; off += (size_t)B_ * N2_;
    float* counts = ws + off; off += (size_t)B_ * N2_;
    size_t zbytes = (size_t)((ws + off) - zblock) * sizeof(float);

    hipMemsetAsync(zblock, 0, zbytes, stream);
    rates_kernel<<<256, 256, 0, stream>>>(x, W_enc, b_enc, rates);
    layer0_kernel<<<256, 256, 0, stream>>>(u, rates, s0_all, p0_all);
    for (int t = 0; t < T_; ++t) {
        int store_w = (t < T_ - 1) ? 1 : 0;
        ka_kernel<<<1024, 256, 0, stream>>>(Wa, s0_all, p0_all, s1_bj, q0_bj, pa, t, store_w);
        lif1_kernel<<<256, 256, 0, stream>>>(pa, V1, r1, s1_bj, s1_jb, q0_bj, p1_jb, t);
        kb_kernel<<<1024, 256, 0, stream>>>(Wb, s1_jb, p1_jb, s2_bk, q1_bk, pb, t, store_w);
        lif2_kernel<<<128, 256, 0, stream>>>(pb, V2, r2, s2_bk, q1_bk, counts, t);
    }
    decode_kernel<<<1, 256, 0, stream>>>(counts, W_dec, b_dec, out);
}

// Round 4
// 8958.184 us; speedup vs baseline: 2.6868x; 2.6868x over previous
//
#include <hip/hip_runtime.h>
#include <math.h>

#define B_  16
#define D_  2048
#define T_  100
#define N0_ 4096
#define N1_ 4096
#define N2_ 2048
#define NC_ 10

// ---------------- rates = sigmoid(x @ W_enc + b_enc) ----------------
__global__ __launch_bounds__(256) void rates_kernel(
    const float* __restrict__ x, const float* __restrict__ W_enc,
    const float* __restrict__ b_enc, float* __restrict__ rates)
{
    int tid = blockIdx.x * 256 + threadIdx.x;      // 65536 = B*N0
    int b = tid >> 12, i = tid & (N0_ - 1);
    const float* xr = x + b * D_;
    float acc = 0.f;
    for (int d = 0; d < D_; ++d)
        acc = fmaf(xr[d], W_enc[(size_t)d * N0_ + i], acc);
    float z = __fadd_rn(acc, b_enc[i]);
    rates[tid] = 1.0f / (1.0f + expf(-z));         // (B, N0)
}

// ---- layer-0 LIF over all T (independent of weights): s0, p0 in (T,N0,B) ----
__global__ __launch_bounds__(256) void layer0_kernel(
    const float* __restrict__ u, const float* __restrict__ rates,
    float* __restrict__ s0_all, float* __restrict__ p0_all)
{
    int tid = blockIdx.x * 256 + threadIdx.x;      // 65536
    int b = tid & (B_ - 1), i = tid >> 4;
    float rate = rates[b * N0_ + i];
    const float* ub = u + (size_t)b * T_ * N0_ + i;  // u is (B,T,N0)
    float V = 0.f, refr = 0.f, p0 = 0.f;
    for (int t = 0; t < T_; ++t) {
        float uv = ub[(size_t)t * N0_];
        float s_in = (uv < rate) ? 1.0f : 0.0f;
        V = __fadd_rn(__fmul_rn(0.9f, V), s_in);
        bool spk = (V > 1.0f) && (refr <= 0.0f);
        float s = spk ? 1.0f : 0.0f;
        V = spk ? 0.0f : V;
        refr = spk ? 2.0f : fmaxf(refr - 1.0f, 0.0f);
        p0 = __fadd_rn(__fmul_rn(0.95f, p0), s);   // trace after spike, per reference
        size_t idx = ((size_t)t * N0_ + i) * B_ + b;
        s0_all[idx] = s;
        p0_all[idx] = p0;
    }
}

// dot16 in fixed b-ascending order
__device__ __forceinline__ float dot16(const float4 r[4], const float* v) {
    float t = 0.f;
    t = fmaf(r[0].x, v[0], t);  t = fmaf(r[0].y, v[1], t);
    t = fmaf(r[0].z, v[2], t);  t = fmaf(r[0].w, v[3], t);
    t = fmaf(r[1].x, v[4], t);  t = fmaf(r[1].y, v[5], t);
    t = fmaf(r[1].z, v[6], t);  t = fmaf(r[1].w, v[7], t);
    t = fmaf(r[2].x, v[8], t);  t = fmaf(r[2].y, v[9], t);
    t = fmaf(r[2].z, v[10], t); t = fmaf(r[2].w, v[11], t);
    t = fmaf(r[3].x, v[12], t); t = fmaf(r[3].y, v[13], t);
    t = fmaf(r[3].z, v[14], t); t = fmaf(r[3].w, v[15], t);
    return t;
}
__device__ __forceinline__ void acc16(float* acc, const float4 r[4], float w) {
    acc[0]  = fmaf(r[0].x, w, acc[0]);  acc[1]  = fmaf(r[0].y, w, acc[1]);
    acc[2]  = fmaf(r[0].z, w, acc[2]);  acc[3]  = fmaf(r[0].w, w, acc[3]);
    acc[4]  = fmaf(r[1].x, w, acc[4]);  acc[5]  = fmaf(r[1].y, w, acc[5]);
    acc[6]  = fmaf(r[1].z, w, acc[6]);  acc[7]  = fmaf(r[1].w, w, acc[7]);
    acc[8]  = fmaf(r[2].x, w, acc[8]);  acc[9]  = fmaf(r[2].y, w, acc[9]);
    acc[10] = fmaf(r[2].z, w, acc[10]); acc[11] = fmaf(r[2].w, w, acc[11]);
    acc[12] = fmaf(r[3].x, w, acc[12]); acc[13] = fmaf(r[3].y, w, acc[13]);
    acc[14] = fmaf(r[3].z, w, acc[14]); acc[15] = fmaf(r[3].w, w, acc[15]);
}
__device__ __forceinline__ void ld_row4(float4 r[4], const float* p) {
    const float4* p4 = (const float4*)p;   // 64B-aligned (i*B_*4); wave-uniform addr -> scalar loads
    r[0] = p4[0]; r[1] = p4[1]; r[2] = p4[2]; r[3] = p4[3];
}

// ---- fused: apply dWa(t-1)+clip, then partial y1(t) = s0(t) @ Wa ----
// grid 1024: 16 j-tiles(256, 1 col/thread) x 64 i-chunks(64 rows) -> 4 blocks/CU.
// Weight stream: 4-row rolling prefetch (covers ~520 cyc of L3 latency) +
// non-temporal loads/stores (pure streaming, keep L2 for row/broadcast data).
// Row loads stay as wave-uniform global loads (compiler issues scalar loads).
__global__ __launch_bounds__(256, 4) void ka_kernel(
    float* __restrict__ Wa,            // (N0, N1) in-place
    const float* __restrict__ s0_all,  // (T, N0, B)
    const float* __restrict__ p0_all,  // (T, N0, B)
    const float* __restrict__ s1_bj,   // (2, B, N1)
    const float* __restrict__ q0_bj,   // (2, B, N1)
    float* __restrict__ pa, int t, int store_w)
{
    const int jt = blockIdx.x >> 6;         // 0..15
    const int chunk = blockIdx.x & 63;      // 0..63
    const int j0 = jt * 256 + threadIdx.x;
    const int i0 = chunk * 64;
    const int prev = 1 - (t & 1);

    float acc0[B_];
    #pragma unroll
    for (int b = 0; b < B_; ++b) acc0[b] = 0.f;

    const float* s0t = s0_all + (size_t)t * N0_ * B_;

    if (t > 0) {
        float s1v0[B_], q0v0[B_];
        #pragma unroll
        for (int b = 0; b < B_; ++b) {
            s1v0[b] = s1_bj[((size_t)prev * B_ + b) * N1_ + j0];
            q0v0[b] = q0_bj[((size_t)prev * B_ + b) * N1_ + j0];
        }
        const float* s0p = s0_all + (size_t)(t - 1) * N0_ * B_;
        const float* p0p = p0_all + (size_t)(t - 1) * N0_ * B_;
        float* wp = Wa + (size_t)i0 * N1_ + j0;
        float wbuf[4];
        #pragma unroll
        for (int g = 0; g < 4; ++g)
            wbuf[g] = __builtin_nontemporal_load(&wp[(size_t)g * N1_]);
        #pragma unroll 4
        for (int ii = 0; ii < 64; ++ii) {
            const float wcur = wbuf[ii & 3];
            if (ii < 60)
                wbuf[ii & 3] = __builtin_nontemporal_load(&wp[(size_t)(ii + 4) * N1_]);
            const int i = i0 + ii;
            float4 p0r[4], s0r[4], s0tr[4];
            ld_row4(p0r,  p0p + (size_t)i * B_);
            ld_row4(s0r,  s0p + (size_t)i * B_);
            ld_row4(s0tr, s0t + (size_t)i * B_);
            float t1a = dot16(p0r, s1v0), t2a = dot16(s0r, q0v0);
            float wn0 = __fadd_rn(wcur, __fmul_rn(0.01f, __fsub_rn(t1a, t2a)));
            wn0 = fminf(fmaxf(wn0, -1.0f), 1.0f);
            if (store_w)
                __builtin_nontemporal_store(wn0, &wp[(size_t)ii * N1_]);
            acc16(acc0, s0tr, wn0);
        }
    } else {
        #pragma unroll 2
        for (int ii = 0; ii < 64; ++ii) {
            const int i = i0 + ii;
            float4 s0tr[4];
            ld_row4(s0tr, s0t + (size_t)i * B_);
            float w0 = __builtin_nontemporal_load(&Wa[(size_t)i * N1_ + j0]);
            acc16(acc0, s0tr, w0);
        }
    }
    #pragma unroll
    for (int b = 0; b < B_; ++b)
        pa[((size_t)chunk * B_ + b) * N1_ + j0] = acc0[b];
}

// ---- LIF layer 1: reduce pa (fixed order, 64 chunks), V1/r1, s1, q0, p1 ----
__global__ __launch_bounds__(256) void lif1_kernel(
    const float* __restrict__ pa, float* __restrict__ V1, float* __restrict__ r1,
    float* __restrict__ s1_bj, float* __restrict__ s1_jb,
    float* __restrict__ q0_bj, float* __restrict__ p1_jb, int t)
{
    int tid = blockIdx.x * 256 + threadIdx.x;      // 65536 = B*N1
    int b = tid >> 12, j = tid & (N1_ - 1);
    float y = 0.f;
    #pragma unroll 16
    for (int c = 0; c < 64; ++c) y += pa[((size_t)c * B_ + b) * N1_ + j];
    float V = __fadd_rn(__fmul_rn(0.9f, V1[tid]), y);
    float rr = r1[tid];
    bool spk = (V > 1.0f) && (rr <= 0.0f);
    float s = spk ? 1.0f : 0.0f;
    V1[tid] = spk ? 0.0f : V;
    r1[tid] = spk ? 2.0f : fmaxf(rr - 1.0f, 0.0f);
    int cur = t & 1, prev = 1 - cur;
    s1_bj[(size_t)cur * B_ * N1_ + tid] = s;
    s1_jb[(size_t)cur * B_ * N1_ + (size_t)j * B_ + b] = s;
    float q0 = __fadd_rn(__fmul_rn(0.95f, q0_bj[(size_t)prev * B_ * N1_ + tid]), s);
    q0_bj[(size_t)cur * B_ * N1_ + tid] = q0;
    float p1 = __fadd_rn(__fmul_rn(0.95f, p1_jb[(size_t)prev * B_ * N1_ + (size_t)j * B_ + b]), s);
    p1_jb[(size_t)cur * B_ * N1_ + (size_t)j * B_ + b] = p1;
}

// ---- fused: apply dWb(t-1)+clip, then partial y2(t) = s1(t) @ Wb ----
// grid 1024: 8 k-tiles(256, 1 col/thread) x 128 j-chunks(32 rows) -> 4 blocks/CU.
__global__ __launch_bounds__(256, 4) void kb_kernel(
    float* __restrict__ Wb,            // (N1, N2) in-place
    const float* __restrict__ s1_jb,   // (2, N1, B)
    const float* __restrict__ p1_jb,   // (2, N1, B)
    const float* __restrict__ s2_bk,   // (2, B, N2)
    const float* __restrict__ q1_bk,   // (2, B, N2)
    float* __restrict__ pb, int t, int store_w)
{
    const int kt = blockIdx.x >> 7;         // 0..7
    const int chunk = blockIdx.x & 127;     // 0..127
    const int k0 = kt * 256 + threadIdx.x;
    const int j0 = chunk * 32;
    const int cur = t & 1, prev = 1 - cur;

    float acc0[B_];
    #pragma unroll
    for (int b = 0; b < B_; ++b) acc0[b] = 0.f;

    const float* s1c = s1_jb + (size_t)cur * N1_ * B_;

    if (t > 0) {
        float s2v0[B_], q1v0[B_];
        #pragma unroll
        for (int b = 0; b < B_; ++b) {
            s2v0[b] = s2_bk[((size_t)prev * B_ + b) * N2_ + k0];
            q1v0[b] = q1_bk[((size_t)prev * B_ + b) * N2_ + k0];
        }
        const float* p1p = p1_jb + (size_t)prev * N1_ * B_;
        const float* s1p = s1_jb + (size_t)prev * N1_ * B_;
        float* wp = Wb + (size_t)j0 * N2_ + k0;
        float wbuf[4];
        #pragma unroll
        for (int g = 0; g < 4; ++g)
            wbuf[g] = __builtin_nontemporal_load(&wp[(size_t)g * N2_]);
        #pragma unroll 4
        for (int jj = 0; jj < 32; ++jj) {
            const float wcur = wbuf[jj & 3];
            if (jj < 28)
                wbuf[jj & 3] = __builtin_nontemporal_load(&wp[(size_t)(jj + 4) * N2_]);
            const int j = j0 + jj;
            float4 p1r[4], s1pr[4], s1cr[4];
            ld_row4(p1r,  p1p + (size_t)j * B_);
            ld_row4(s1pr, s1p + (size_t)j * B_);
            ld_row4(s1cr, s1c + (size_t)j * B_);
            float t1a = dot16(p1r, s2v0), t2a = dot16(s1pr, q1v0);
            float wn0 = __fadd_rn(wcur, __fmul_rn(0.01f, __fsub_rn(t1a, t2a)));
            wn0 = fminf(fmaxf(wn0, -1.0f), 1.0f);
            if (store_w)
                __builtin_nontemporal_store(wn0, &wp[(size_t)jj * N2_]);
            acc16(acc0, s1cr, wn0);
        }
    } else {
        #pragma unroll 2
        for (int jj = 0; jj < 32; ++jj) {
            const int j = j0 + jj;
            float4 s1cr[4];
            ld_row4(s1cr, s1c + (size_t)j * B_);
            float w0 = __builtin_nontemporal_load(&Wb[(size_t)j * N2_ + k0]);
            acc16(acc0, s1cr, w0);
        }
    }
    #pragma unroll
    for (int b = 0; b < B_; ++b)
        pb[((size_t)chunk * B_ + b) * N2_ + k0] = acc0[b];
}

// ---- LIF layer 2: reduce pb (128 chunks), V2/r2, s2, q1, spike counts ----
// grid 256 x 128 threads: same tid->output map as before, but all 256 CUs busy.
__global__ __launch_bounds__(128) void lif2_kernel(
    const float* __restrict__ pb, float* __restrict__ V2, float* __restrict__ r2,
    float* __restrict__ s2_bk, float* __restrict__ q1_bk,
    float* __restrict__ counts, int t)
{
    int tid = blockIdx.x * 128 + threadIdx.x;      // 32768 = B*N2
    int b = tid >> 11, k = tid & (N2_ - 1);
    float y = 0.f;
    #pragma unroll 16
    for (int c = 0; c < 128; ++c) y += pb[((size_t)c * B_ + b) * N2_ + k];
    float V = __fadd_rn(__fmul_rn(0.9f, V2[tid]), y);
    float rr = r2[tid];
    bool spk = (V > 1.0f) && (rr <= 0.0f);
    float s = spk ? 1.0f : 0.0f;
    V2[tid] = spk ? 0.0f : V;
    r2[tid] = spk ? 2.0f : fmaxf(rr - 1.0f, 0.0f);
    int cur = t & 1, prev = 1 - cur;
    s2_bk[(size_t)cur * B_ * N2_ + tid] = s;
    float q1 = __fadd_rn(__fmul_rn(0.95f, q1_bk[(size_t)prev * B_ * N2_ + tid]), s);
    q1_bk[(size_t)cur * B_ * N2_ + tid] = q1;
    counts[tid] = counts[tid] + s;
}

// ---- decode: out = counts @ W_dec + b_dec ----
__global__ __launch_bounds__(256) void decode_kernel(
    const float* __restrict__ counts, const float* __restrict__ W_dec,
    const float* __restrict__ b_dec, float* __restrict__ out)
{
    int tid = threadIdx.x;
    if (tid < B_ * NC_) {
        int b = tid / NC_, c = tid % NC_;
        float a = 0.f;
        for (int k = 0; k < N2_; ++k)
            a = fmaf(counts[(size_t)b * N2_ + k], W_dec[(size_t)k * NC_ + c], a);
        out[tid] = __fadd_rn(a, b_dec[c]);
    }
}

extern "C" void kernel_launch(void* const* d_in, const int* in_sizes, int n_in,
                              void* d_out, int out_size, void* d_ws, size_t ws_size,
                              hipStream_t stream) {
    const float* x     = (const float*)d_in[0];
    const float* u     = (const float*)d_in[1];
    const float* W_enc = (const float*)d_in[2];
    const float* b_enc = (const float*)d_in[3];
    float* Wa          = (float*)d_in[4];   // updated in place; harness restores before every timed launch
    float* Wb          = (float*)d_in[5];
    const float* W_dec = (const float*)d_in[6];
    const float* b_dec = (const float*)d_in[7];
    float* out         = (float*)d_out;

    float* ws = (float*)d_ws;
    size_t off = 0;
    float* rates  = ws + off; off += (size_t)B_ * N0_;
    float* s0_all = ws + off; off += (size_t)T_ * N0_ * B_;
    float* p0_all = ws + off; off += (size_t)T_ * N0_ * B_;
    float* s1_bj  = ws + off; off += 2 * (size_t)B_ * N1_;
    float* s1_jb  = ws + off; off += 2 * (size_t)B_ * N1_;
    float* pa     = ws + off; off += 64 * (size_t)B_ * N1_;
    float* pb     = ws + off; off += 128 * (size_t)B_ * N2_;
    float* zblock = ws + off;                       // everything below is zero-init state
    float* q0_bj  = ws + off; off += 2 * (size_t)B_ * N1_;
    float* p1_jb  = ws + off; off += 2 * (size_t)B_ * N1_;
    float* q1_bk  = ws + off; off += 2 * (size_t)B_ * N2_;
    float* s2_bk  = ws + off; off += 2 * (size_t)B_ * N2_;
    float* V1     = ws + off; off += (size_t)B_ * N1_;
    float* r1     = ws + off; off += (size_t)B_ * N1_;
    float* V2     = ws + off; off += (size_t)B_ * N2_;
    float* r2     = ws + off; off += (size_t)B_ * N2_;
    float* counts = ws + off; off += (size_t)B_ * N2_;
    size_t zbytes = (size_t)((ws + off) - zblock) * sizeof(float);

    hipMemsetAsync(zblock, 0, zbytes, stream);
    rates_kernel<<<256, 256, 0, stream>>>(x, W_enc, b_enc, rates);
    layer0_kernel<<<256, 256, 0, stream>>>(u, rates, s0_all, p0_all);
    for (int t = 0; t < T_; ++t) {
        int store_w = (t < T_ - 1) ? 1 : 0;
        ka_kernel<<<1024, 256, 0, stream>>>(Wa, s0_all, p0_all, s1_bj, q0_bj, pa, t, store_w);
        lif1_kernel<<<256, 256, 0, stream>>>(pa, V1, r1, s1_bj, s1_jb, q0_bj, p1_jb, t);
        kb_kernel<<<1024, 256, 0, stream>>>(Wb, s1_jb, p1_jb, s2_bk, q1_bk, pb, t, store_w);
        lif2_kernel<<<256, 128, 0, stream>>>(pb, V2, r2, s2_bk, q1_bk, counts, t);
    }
    decode_kernel<<<1, 256, 0, stream>>>(counts, W_dec, b_dec, out);
}

// Round 5
// 8022.766 us; speedup vs baseline: 3.0001x; 1.1166x over previous
//
#include <hip/hip_runtime.h>
#include <math.h>

#define B_  16
#define D_  2048
#define T_  100
#define N0_ 4096
#define N1_ 4096
#define N2_ 2048
#define NC_ 10

// ---------------- rates = sigmoid(x @ W_enc + b_enc) ----------------
__global__ __launch_bounds__(256) void rates_kernel(
    const float* __restrict__ x, const float* __restrict__ W_enc,
    const float* __restrict__ b_enc, float* __restrict__ rates)
{
    int tid = blockIdx.x * 256 + threadIdx.x;      // 65536 = B*N0
    int b = tid >> 12, i = tid & (N0_ - 1);
    const float* xr = x + b * D_;
    float acc = 0.f;
    for (int d = 0; d < D_; ++d)
        acc = fmaf(xr[d], W_enc[(size_t)d * N0_ + i], acc);
    float z = __fadd_rn(acc, b_enc[i]);
    rates[tid] = 1.0f / (1.0f + expf(-z));         // (B, N0)
}

// ---- layer-0 LIF over all T (independent of weights): s0, p0 in (T,N0,B) ----
__global__ __launch_bounds__(256) void layer0_kernel(
    const float* __restrict__ u, const float* __restrict__ rates,
    float* __restrict__ s0_all, float* __restrict__ p0_all)
{
    int tid = blockIdx.x * 256 + threadIdx.x;      // 65536
    int b = tid & (B_ - 1), i = tid >> 4;
    float rate = rates[b * N0_ + i];
    const float* ub = u + (size_t)b * T_ * N0_ + i;  // u is (B,T,N0)
    float V = 0.f, refr = 0.f, p0 = 0.f;
    for (int t = 0; t < T_; ++t) {
        float uv = ub[(size_t)t * N0_];
        float s_in = (uv < rate) ? 1.0f : 0.0f;
        V = __fadd_rn(__fmul_rn(0.9f, V), s_in);
        bool spk = (V > 1.0f) && (refr <= 0.0f);
        float s = spk ? 1.0f : 0.0f;
        V = spk ? 0.0f : V;
        refr = spk ? 2.0f : fmaxf(refr - 1.0f, 0.0f);
        p0 = __fadd_rn(__fmul_rn(0.95f, p0), s);   // trace after spike, per reference
        size_t idx = ((size_t)t * N0_ + i) * B_ + b;
        s0_all[idx] = s;
        p0_all[idx] = p0;
    }
}

// dot16 in fixed b-ascending order
__device__ __forceinline__ float dot16(const float4 r[4], const float* v) {
    float t = 0.f;
    t = fmaf(r[0].x, v[0], t);  t = fmaf(r[0].y, v[1], t);
    t = fmaf(r[0].z, v[2], t);  t = fmaf(r[0].w, v[3], t);
    t = fmaf(r[1].x, v[4], t);  t = fmaf(r[1].y, v[5], t);
    t = fmaf(r[1].z, v[6], t);  t = fmaf(r[1].w, v[7], t);
    t = fmaf(r[2].x, v[8], t);  t = fmaf(r[2].y, v[9], t);
    t = fmaf(r[2].z, v[10], t); t = fmaf(r[2].w, v[11], t);
    t = fmaf(r[3].x, v[12], t); t = fmaf(r[3].y, v[13], t);
    t = fmaf(r[3].z, v[14], t); t = fmaf(r[3].w, v[15], t);
    return t;
}
__device__ __forceinline__ void acc16(float* acc, const float4 r[4], float w) {
    acc[0]  = fmaf(r[0].x, w, acc[0]);  acc[1]  = fmaf(r[0].y, w, acc[1]);
    acc[2]  = fmaf(r[0].z, w, acc[2]);  acc[3]  = fmaf(r[0].w, w, acc[3]);
    acc[4]  = fmaf(r[1].x, w, acc[4]);  acc[5]  = fmaf(r[1].y, w, acc[5]);
    acc[6]  = fmaf(r[1].z, w, acc[6]);  acc[7]  = fmaf(r[1].w, w, acc[7]);
    acc[8]  = fmaf(r[2].x, w, acc[8]);  acc[9]  = fmaf(r[2].y, w, acc[9]);
    acc[10] = fmaf(r[2].z, w, acc[10]); acc[11] = fmaf(r[2].w, w, acc[11]);
    acc[12] = fmaf(r[3].x, w, acc[12]); acc[13] = fmaf(r[3].y, w, acc[13]);
    acc[14] = fmaf(r[3].z, w, acc[14]); acc[15] = fmaf(r[3].w, w, acc[15]);
}
__device__ __forceinline__ void ld_row4(float4 r[4], const float* p) {
    const float4* p4 = (const float4*)p;   // 64B-aligned (i*B_*4); wave-uniform addr -> scalar loads
    r[0] = p4[0]; r[1] = p4[1]; r[2] = p4[2]; r[3] = p4[3];
}

// ---- fused: apply dWa(t-1)+clip, then partial y1(t) = s0(t) @ Wa ----
// grid 1024: 16 j-tiles(256, 1 col/thread) x 64 i-chunks(64 rows) -> 4 blocks/CU.
// Weight stream: 4-row rolling prefetch (regular cached loads — weights are
// L3-resident and re-read every timestep; nontemporal was a 1.5ms regression).
__global__ __launch_bounds__(256, 4) void ka_kernel(
    float* __restrict__ Wa,            // (N0, N1) in-place
    const float* __restrict__ s0_all,  // (T, N0, B)
    const float* __restrict__ p0_all,  // (T, N0, B)
    const float* __restrict__ s1_bj,   // (2, B, N1)
    const float* __restrict__ q0_bj,   // (2, B, N1)
    float* __restrict__ pa, int t, int store_w)
{
    const int jt = blockIdx.x >> 6;         // 0..15
    const int chunk = blockIdx.x & 63;      // 0..63
    const int j0 = jt * 256 + threadIdx.x;
    const int i0 = chunk * 64;
    const int prev = 1 - (t & 1);

    float acc0[B_];
    #pragma unroll
    for (int b = 0; b < B_; ++b) acc0[b] = 0.f;

    const float* s0t = s0_all + (size_t)t * N0_ * B_;

    if (t > 0) {
        float s1v0[B_], q0v0[B_];
        #pragma unroll
        for (int b = 0; b < B_; ++b) {
            s1v0[b] = s1_bj[((size_t)prev * B_ + b) * N1_ + j0];
            q0v0[b] = q0_bj[((size_t)prev * B_ + b) * N1_ + j0];
        }
        const float* s0p = s0_all + (size_t)(t - 1) * N0_ * B_;
        const float* p0p = p0_all + (size_t)(t - 1) * N0_ * B_;
        float* wp = Wa + (size_t)i0 * N1_ + j0;
        float wbuf[4];
        #pragma unroll
        for (int g = 0; g < 4; ++g)
            wbuf[g] = wp[(size_t)g * N1_];
        #pragma unroll 4
        for (int ii = 0; ii < 64; ++ii) {
            const float wcur = wbuf[ii & 3];
            if (ii < 60)
                wbuf[ii & 3] = wp[(size_t)(ii + 4) * N1_];
            const int i = i0 + ii;
            float4 p0r[4], s0r[4], s0tr[4];
            ld_row4(p0r,  p0p + (size_t)i * B_);
            ld_row4(s0r,  s0p + (size_t)i * B_);
            ld_row4(s0tr, s0t + (size_t)i * B_);
            float t1a = dot16(p0r, s1v0), t2a = dot16(s0r, q0v0);
            float wn0 = __fadd_rn(wcur, __fmul_rn(0.01f, __fsub_rn(t1a, t2a)));
            wn0 = fminf(fmaxf(wn0, -1.0f), 1.0f);
            if (store_w)
                wp[(size_t)ii * N1_] = wn0;
            acc16(acc0, s0tr, wn0);
        }
    } else {
        #pragma unroll 2
        for (int ii = 0; ii < 64; ++ii) {
            const int i = i0 + ii;
            float4 s0tr[4];
            ld_row4(s0tr, s0t + (size_t)i * B_);
            float w0 = Wa[(size_t)i * N1_ + j0];
            acc16(acc0, s0tr, w0);
        }
    }
    #pragma unroll
    for (int b = 0; b < B_; ++b)
        pa[((size_t)chunk * B_ + b) * N1_ + j0] = acc0[b];
}

// ---- LIF layer 1: reduce pa (fixed order, 64 chunks), V1/r1, s1, q0, p1 ----
__global__ __launch_bounds__(256) void lif1_kernel(
    const float* __restrict__ pa, float* __restrict__ V1, float* __restrict__ r1,
    float* __restrict__ s1_bj, float* __restrict__ s1_jb,
    float* __restrict__ q0_bj, float* __restrict__ p1_jb, int t)
{
    int tid = blockIdx.x * 256 + threadIdx.x;      // 65536 = B*N1
    int b = tid >> 12, j = tid & (N1_ - 1);
    float y = 0.f;
    #pragma unroll 16
    for (int c = 0; c < 64; ++c) y += pa[((size_t)c * B_ + b) * N1_ + j];
    float V = __fadd_rn(__fmul_rn(0.9f, V1[tid]), y);
    float rr = r1[tid];
    bool spk = (V > 1.0f) && (rr <= 0.0f);
    float s = spk ? 1.0f : 0.0f;
    V1[tid] = spk ? 0.0f : V;
    r1[tid] = spk ? 2.0f : fmaxf(rr - 1.0f, 0.0f);
    int cur = t & 1, prev = 1 - cur;
    s1_bj[(size_t)cur * B_ * N1_ + tid] = s;
    s1_jb[(size_t)cur * B_ * N1_ + (size_t)j * B_ + b] = s;
    float q0 = __fadd_rn(__fmul_rn(0.95f, q0_bj[(size_t)prev * B_ * N1_ + tid]), s);
    q0_bj[(size_t)cur * B_ * N1_ + tid] = q0;
    float p1 = __fadd_rn(__fmul_rn(0.95f, p1_jb[(size_t)prev * B_ * N1_ + (size_t)j * B_ + b]), s);
    p1_jb[(size_t)cur * B_ * N1_ + (size_t)j * B_ + b] = p1;
}

// ---- fused: apply dWb(t-1)+clip, then partial y2(t) = s1(t) @ Wb ----
// grid 1024: 8 k-tiles(256, 1 col/thread) x 128 j-chunks(32 rows) -> 4 blocks/CU.
__global__ __launch_bounds__(256, 4) void kb_kernel(
    float* __restrict__ Wb,            // (N1, N2) in-place
    const float* __restrict__ s1_jb,   // (2, N1, B)
    const float* __restrict__ p1_jb,   // (2, N1, B)
    const float* __restrict__ s2_bk,   // (2, B, N2)
    const float* __restrict__ q1_bk,   // (2, B, N2)
    float* __restrict__ pb, int t, int store_w)
{
    const int kt = blockIdx.x >> 7;         // 0..7
    const int chunk = blockIdx.x & 127;     // 0..127
    const int k0 = kt * 256 + threadIdx.x;
    const int j0 = chunk * 32;
    const int cur = t & 1, prev = 1 - cur;

    float acc0[B_];
    #pragma unroll
    for (int b = 0; b < B_; ++b) acc0[b] = 0.f;

    const float* s1c = s1_jb + (size_t)cur * N1_ * B_;

    if (t > 0) {
        float s2v0[B_], q1v0[B_];
        #pragma unroll
        for (int b = 0; b < B_; ++b) {
            s2v0[b] = s2_bk[((size_t)prev * B_ + b) * N2_ + k0];
            q1v0[b] = q1_bk[((size_t)prev * B_ + b) * N2_ + k0];
        }
        const float* p1p = p1_jb + (size_t)prev * N1_ * B_;
        const float* s1p = s1_jb + (size_t)prev * N1_ * B_;
        float* wp = Wb + (size_t)j0 * N2_ + k0;
        float wbuf[4];
        #pragma unroll
        for (int g = 0; g < 4; ++g)
            wbuf[g] = wp[(size_t)g * N2_];
        #pragma unroll 4
        for (int jj = 0; jj < 32; ++jj) {
            const float wcur = wbuf[jj & 3];
            if (jj < 28)
                wbuf[jj & 3] = wp[(size_t)(jj + 4) * N2_];
            const int j = j0 + jj;
            float4 p1r[4], s1pr[4], s1cr[4];
            ld_row4(p1r,  p1p + (size_t)j * B_);
            ld_row4(s1pr, s1p + (size_t)j * B_);
            ld_row4(s1cr, s1c + (size_t)j * B_);
            float t1a = dot16(p1r, s2v0), t2a = dot16(s1pr, q1v0);
            float wn0 = __fadd_rn(wcur, __fmul_rn(0.01f, __fsub_rn(t1a, t2a)));
            wn0 = fminf(fmaxf(wn0, -1.0f), 1.0f);
            if (store_w)
                wp[(size_t)jj * N2_] = wn0;
            acc16(acc0, s1cr, wn0);
        }
    } else {
        #pragma unroll 2
        for (int jj = 0; jj < 32; ++jj) {
            const int j = j0 + jj;
            float4 s1cr[4];
            ld_row4(s1cr, s1c + (size_t)j * B_);
            float w0 = Wb[(size_t)j * N2_ + k0];
            acc16(acc0, s1cr, w0);
        }
    }
    #pragma unroll
    for (int b = 0; b < B_; ++b)
        pb[((size_t)chunk * B_ + b) * N2_ + k0] = acc0[b];
}

// ---- LIF layer 2: reduce pb (128 chunks), V2/r2, s2, q1, spike counts ----
// grid 256 x 128 threads: same tid->output map as before, but all 256 CUs busy.
__global__ __launch_bounds__(128) void lif2_kernel(
    const float* __restrict__ pb, float* __restrict__ V2, float* __restrict__ r2,
    float* __restrict__ s2_bk, float* __restrict__ q1_bk,
    float* __restrict__ counts, int t)
{
    int tid = blockIdx.x * 128 + threadIdx.x;      // 32768 = B*N2
    int b = tid >> 11, k = tid & (N2_ - 1);
    float y = 0.f;
    #pragma unroll 16
    for (int c = 0; c < 128; ++c) y += pb[((size_t)c * B_ + b) * N2_ + k];
    float V = __fadd_rn(__fmul_rn(0.9f, V2[tid]), y);
    float rr = r2[tid];
    bool spk = (V > 1.0f) && (rr <= 0.0f);
    float s = spk ? 1.0f : 0.0f;
    V2[tid] = spk ? 0.0f : V;
    r2[tid] = spk ? 2.0f : fmaxf(rr - 1.0f, 0.0f);
    int cur = t & 1, prev = 1 - cur;
    s2_bk[(size_t)cur * B_ * N2_ + tid] = s;
    float q1 = __fadd_rn(__fmul_rn(0.95f, q1_bk[(size_t)prev * B_ * N2_ + tid]), s);
    q1_bk[(size_t)cur * B_ * N2_ + tid] = q1;
    counts[tid] = counts[tid] + s;
}

// ---- decode: out = counts @ W_dec + b_dec ----
__global__ __launch_bounds__(256) void decode_kernel(
    const float* __restrict__ counts, const float* __restrict__ W_dec,
    const float* __restrict__ b_dec, float* __restrict__ out)
{
    int tid = threadIdx.x;
    if (tid < B_ * NC_) {
        int b = tid / NC_, c = tid % NC_;
        float a = 0.f;
        for (int k = 0; k < N2_; ++k)
            a = fmaf(counts[(size_t)b * N2_ + k], W_dec[(size_t)k * NC_ + c], a);
        out[tid] = __fadd_rn(a, b_dec[c]);
    }
}

extern "C" void kernel_launch(void* const* d_in, const int* in_sizes, int n_in,
                              void* d_out, int out_size, void* d_ws, size_t ws_size,
                              hipStream_t stream) {
    const float* x     = (const float*)d_in[0];
    const float* u     = (const float*)d_in[1];
    const float* W_enc = (const float*)d_in[2];
    const float* b_enc = (const float*)d_in[3];
    float* Wa          = (float*)d_in[4];   // updated in place; harness restores before every timed launch
    float* Wb          = (float*)d_in[5];
    const float* W_dec = (const float*)d_in[6];
    const float* b_dec = (const float*)d_in[7];
    float* out         = (float*)d_out;

    float* ws = (float*)d_ws;
    size_t off = 0;
    float* rates  = ws + off; off += (size_t)B_ * N0_;
    float* s0_all = ws + off; off += (size_t)T_ * N0_ * B_;
    float* p0_all = ws + off; off += (size_t)T_ * N0_ * B_;
    float* s1_bj  = ws + off; off += 2 * (size_t)B_ * N1_;
    float* s1_jb  = ws + off; off += 2 * (size_t)B_ * N1_;
    float* pa     = ws + off; off += 64 * (size_t)B_ * N1_;
    float* pb     = ws + off; off += 128 * (size_t)B_ * N2_;
    float* zblock = ws + off;                       // everything below is zero-init state
    float* q0_bj  = ws + off; off += 2 * (size_t)B_ * N1_;
    float* p1_jb  = ws + off; off += 2 * (size_t)B_ * N1_;
    float* q1_bk  = ws + off; off += 2 * (size_t)B_ * N2_;
    float* s2_bk  = ws + off; off += 2 * (size_t)B_ * N2_;
    float* V1     = ws + off; off += (size_t)B_ * N1_;
    float* r1     = ws + off; off += (size_t)B_ * N1_;
    float* V2     = ws + off; off += (size_t)B_ * N2_;
    float* r2     = ws + off; off += (size_t)B_ * N2_;
    float* counts = ws + off; off += (size_t)B_ * N2_;
    size_t zbytes = (size_t)((ws + off) - zblock) * sizeof(float);

    hipMemsetAsync(zblock, 0, zbytes, stream);
    rates_kernel<<<256, 256, 0, stream>>>(x, W_enc, b_enc, rates);
    layer0_kernel<<<256, 256, 0, stream>>>(u, rates, s0_all, p0_all);
    for (int t = 0; t < T_; ++t) {
        int store_w = (t < T_ - 1) ? 1 : 0;
        ka_kernel<<<1024, 256, 0, stream>>>(Wa, s0_all, p0_all, s1_bj, q0_bj, pa, t, store_w);
        lif1_kernel<<<256, 256, 0, stream>>>(pa, V1, r1, s1_bj, s1_jb, q0_bj, p1_jb, t);
        kb_kernel<<<1024, 256, 0, stream>>>(Wb, s1_jb, p1_jb, s2_bk, q1_bk, pb, t, store_w);
        lif2_kernel<<<256, 128, 0, stream>>>(pb, V2, r2, s2_bk, q1_bk, counts, t);
    }
    decode_kernel<<<1, 256, 0, stream>>>(counts, W_dec, b_dec, out);
}

// Round 7
// 6980.014 us; speedup vs baseline: 3.4482x; 1.1494x over previous
//
#include <hip/hip_runtime.h>
#include <math.h>

#define B_  16
#define D_  2048
#define T_  100
#define N0_ 4096
#define N1_ 4096
#define N2_ 2048
#define NC_ 10

// ---------------- rates = sigmoid(x @ W_enc + b_enc) ----------------
__global__ __launch_bounds__(256) void rates_kernel(
    const float* __restrict__ x, const float* __restrict__ W_enc,
    const float* __restrict__ b_enc, float* __restrict__ rates)
{
    int tid = blockIdx.x * 256 + threadIdx.x;      // 65536 = B*N0
    int b = tid >> 12, i = tid & (N0_ - 1);
    const float* xr = x + b * D_;
    float acc = 0.f;
    for (int d = 0; d < D_; ++d)
        acc = fmaf(xr[d], W_enc[(size_t)d * N0_ + i], acc);
    float z = __fadd_rn(acc, b_enc[i]);
    rates[tid] = 1.0f / (1.0f + expf(-z));         // (B, N0)
}

// ---- layer-0 LIF over all T (independent of weights): s0, p0 in (T,N0,B) ----
__global__ __launch_bounds__(256) void layer0_kernel(
    const float* __restrict__ u, const float* __restrict__ rates,
    float* __restrict__ s0_all, float* __restrict__ p0_all)
{
    int tid = blockIdx.x * 256 + threadIdx.x;      // 65536
    int b = tid & (B_ - 1), i = tid >> 4;
    float rate = rates[b * N0_ + i];
    const float* ub = u + (size_t)b * T_ * N0_ + i;  // u is (B,T,N0)
    float V = 0.f, refr = 0.f, p0 = 0.f;
    for (int t = 0; t < T_; ++t) {
        float uv = ub[(size_t)t * N0_];
        float s_in = (uv < rate) ? 1.0f : 0.0f;
        V = __fadd_rn(__fmul_rn(0.9f, V), s_in);
        bool spk = (V > 1.0f) && (refr <= 0.0f);
        float s = spk ? 1.0f : 0.0f;
        V = spk ? 0.0f : V;
        refr = spk ? 2.0f : fmaxf(refr - 1.0f, 0.0f);
        p0 = __fadd_rn(__fmul_rn(0.95f, p0), s);   // trace after spike, per reference
        size_t idx = ((size_t)t * N0_ + i) * B_ + b;
        s0_all[idx] = s;
        p0_all[idx] = p0;
    }
}

// dot16 in fixed b-ascending order
__device__ __forceinline__ float dot16(const float4 r[4], const float* v) {
    float t = 0.f;
    t = fmaf(r[0].x, v[0], t);  t = fmaf(r[0].y, v[1], t);
    t = fmaf(r[0].z, v[2], t);  t = fmaf(r[0].w, v[3], t);
    t = fmaf(r[1].x, v[4], t);  t = fmaf(r[1].y, v[5], t);
    t = fmaf(r[1].z, v[6], t);  t = fmaf(r[1].w, v[7], t);
    t = fmaf(r[2].x, v[8], t);  t = fmaf(r[2].y, v[9], t);
    t = fmaf(r[2].z, v[10], t); t = fmaf(r[2].w, v[11], t);
    t = fmaf(r[3].x, v[12], t); t = fmaf(r[3].y, v[13], t);
    t = fmaf(r[3].z, v[14], t); t = fmaf(r[3].w, v[15], t);
    return t;
}
__device__ __forceinline__ void acc16(float* acc, const float4 r[4], float w) {
    acc[0]  = fmaf(r[0].x, w, acc[0]);  acc[1]  = fmaf(r[0].y, w, acc[1]);
    acc[2]  = fmaf(r[0].z, w, acc[2]);  acc[3]  = fmaf(r[0].w, w, acc[3]);
    acc[4]  = fmaf(r[1].x, w, acc[4]);  acc[5]  = fmaf(r[1].y, w, acc[5]);
    acc[6]  = fmaf(r[1].z, w, acc[6]);  acc[7]  = fmaf(r[1].w, w, acc[7]);
    acc[8]  = fmaf(r[2].x, w, acc[8]);  acc[9]  = fmaf(r[2].y, w, acc[9]);
    acc[10] = fmaf(r[2].z, w, acc[10]); acc[11] = fmaf(r[2].w, w, acc[11]);
    acc[12] = fmaf(r[3].x, w, acc[12]); acc[13] = fmaf(r[3].y, w, acc[13]);
    acc[14] = fmaf(r[3].z, w, acc[14]); acc[15] = fmaf(r[3].w, w, acc[15]);
}
__device__ __forceinline__ void ld_row4(float4 r[4], const float* p) {
    const float4* p4 = (const float4*)p;   // 64B-aligned (i*B_*4); wave-uniform addr -> scalar loads
    r[0] = p4[0]; r[1] = p4[1]; r[2] = p4[2]; r[3] = p4[3];
}

// ---- K1: blocks 0..1023 = ka (apply dWa(t-1)+clip, partial y1(t) = s0(t)@Wa),
//          blocks 1024..1151 = lif2 for step t-1 (data-independent of ka(t);
//          dispatches as ka's blocks drain -> execution hidden, launch saved).
// ka part: exact R1 structure (measured best): 16 j-tiles(256, 1 col/thread)
// x 64 i-chunks(64 rows), 1-row-ahead weight prefetch, cached loads.
__global__ __launch_bounds__(256, 4) void ka_lif2_kernel(
    float* __restrict__ Wa,            // (N0, N1) in-place
    const float* __restrict__ s0_all,  // (T, N0, B)
    const float* __restrict__ p0_all,  // (T, N0, B)
    const float* __restrict__ s1_bj,   // (2, B, N1)
    const float* __restrict__ q0_bj,   // (2, B, N1)
    float* __restrict__ pa,
    const float* __restrict__ pb,      // lif2 inputs/state (for step t-1)
    float* __restrict__ V2, float* __restrict__ r2,
    float* __restrict__ s2_bk, float* __restrict__ q1_bk,
    float* __restrict__ counts,
    int t, int store_w)
{
    if (blockIdx.x >= 1024) {
        // ---------------- lif2 for step t-1 (exact R1 lif2 body) ----------------
        if (t == 0) return;
        const int tm1 = t - 1;
        int tid = (blockIdx.x - 1024) * 256 + threadIdx.x;   // 32768 = B*N2
        int b = tid >> 11, k = tid & (N2_ - 1);
        float y = 0.f;
        #pragma unroll 16
        for (int c = 0; c < 128; ++c) y += pb[((size_t)c * B_ + b) * N2_ + k];
        float V = __fadd_rn(__fmul_rn(0.9f, V2[tid]), y);
        float rr = r2[tid];
        bool spk = (V > 1.0f) && (rr <= 0.0f);
        float s = spk ? 1.0f : 0.0f;
        V2[tid] = spk ? 0.0f : V;
        r2[tid] = spk ? 2.0f : fmaxf(rr - 1.0f, 0.0f);
        int cur = tm1 & 1, prev = 1 - cur;
        s2_bk[(size_t)cur * B_ * N2_ + tid] = s;
        float q1 = __fadd_rn(__fmul_rn(0.95f, q1_bk[(size_t)prev * B_ * N2_ + tid]), s);
        q1_bk[(size_t)cur * B_ * N2_ + tid] = q1;
        counts[tid] = counts[tid] + s;
        return;
    }

    // ---------------- ka (exact R1 body) ----------------
    const int jt = blockIdx.x >> 6;         // 0..15
    const int chunk = blockIdx.x & 63;      // 0..63
    const int j0 = jt * 256 + threadIdx.x;
    const int i0 = chunk * 64;
    const int prev = 1 - (t & 1);

    float acc0[B_];
    #pragma unroll
    for (int b = 0; b < B_; ++b) acc0[b] = 0.f;

    const float* s0t = s0_all + (size_t)t * N0_ * B_;

    if (t > 0) {
        float s1v0[B_], q0v0[B_];
        #pragma unroll
        for (int b = 0; b < B_; ++b) {
            s1v0[b] = s1_bj[((size_t)prev * B_ + b) * N1_ + j0];
            q0v0[b] = q0_bj[((size_t)prev * B_ + b) * N1_ + j0];
        }
        const float* s0p = s0_all + (size_t)(t - 1) * N0_ * B_;
        const float* p0p = p0_all + (size_t)(t - 1) * N0_ * B_;
        float w0 = Wa[(size_t)i0 * N1_ + j0];
        #pragma unroll 2
        for (int ii = 0; ii < 64; ++ii) {
            const int i = i0 + ii;
            const int ip = (ii < 63) ? (i + 1) : i;        // prefetch next row's weight
            float w0n = Wa[(size_t)ip * N1_ + j0];
            float4 p0r[4], s0r[4], s0tr[4];
            ld_row4(p0r,  p0p + (size_t)i * B_);
            ld_row4(s0r,  s0p + (size_t)i * B_);
            ld_row4(s0tr, s0t + (size_t)i * B_);
            float t1a = dot16(p0r, s1v0), t2a = dot16(s0r, q0v0);
            float wn0 = __fadd_rn(w0, __fmul_rn(0.01f, __fsub_rn(t1a, t2a)));
            wn0 = fminf(fmaxf(wn0, -1.0f), 1.0f);
            if (store_w)
                Wa[(size_t)i * N1_ + j0] = wn0;
            acc16(acc0, s0tr, wn0);
            w0 = w0n;
        }
    } else {
        #pragma unroll 2
        for (int ii = 0; ii < 64; ++ii) {
            const int i = i0 + ii;
            float4 s0tr[4];
            ld_row4(s0tr, s0t + (size_t)i * B_);
            float w0 = Wa[(size_t)i * N1_ + j0];
            acc16(acc0, s0tr, w0);
        }
    }
    #pragma unroll
    for (int b = 0; b < B_; ++b)
        pa[((size_t)chunk * B_ + b) * N1_ + j0] = acc0[b];
}

// ---- LIF layer 1: reduce pa (fixed order, 64 chunks), V1/r1, s1, q0, p1 ----
__global__ __launch_bounds__(256) void lif1_kernel(
    const float* __restrict__ pa, float* __restrict__ V1, float* __restrict__ r1,
    float* __restrict__ s1_bj, float* __restrict__ s1_jb,
    float* __restrict__ q0_bj, float* __restrict__ p1_jb, int t)
{
    int tid = blockIdx.x * 256 + threadIdx.x;      // 65536 = B*N1
    int b = tid >> 12, j = tid & (N1_ - 1);
    float y = 0.f;
    #pragma unroll 16
    for (int c = 0; c < 64; ++c) y += pa[((size_t)c * B_ + b) * N1_ + j];
    float V = __fadd_rn(__fmul_rn(0.9f, V1[tid]), y);
    float rr = r1[tid];
    bool spk = (V > 1.0f) && (rr <= 0.0f);
    float s = spk ? 1.0f : 0.0f;
    V1[tid] = spk ? 0.0f : V;
    r1[tid] = spk ? 2.0f : fmaxf(rr - 1.0f, 0.0f);
    int cur = t & 1, prev = 1 - cur;
    s1_bj[(size_t)cur * B_ * N1_ + tid] = s;
    s1_jb[(size_t)cur * B_ * N1_ + (size_t)j * B_ + b] = s;
    float q0 = __fadd_rn(__fmul_rn(0.95f, q0_bj[(size_t)prev * B_ * N1_ + tid]), s);
    q0_bj[(size_t)cur * B_ * N1_ + tid] = q0;
    float p1 = __fadd_rn(__fmul_rn(0.95f, p1_jb[(size_t)prev * B_ * N1_ + (size_t)j * B_ + b]), s);
    p1_jb[(size_t)cur * B_ * N1_ + (size_t)j * B_ + b] = p1;
}

// ---- fused: apply dWb(t-1)+clip, then partial y2(t) = s1(t) @ Wb ----
// grid 1024: 8 k-tiles(256, 1 col/thread) x 128 j-chunks(32 rows) -> 4 blocks/CU.
__global__ __launch_bounds__(256, 4) void kb_kernel(
    float* __restrict__ Wb,            // (N1, N2) in-place
    const float* __restrict__ s1_jb,   // (2, N1, B)
    const float* __restrict__ p1_jb,   // (2, N1, B)
    const float* __restrict__ s2_bk,   // (2, B, N2)
    const float* __restrict__ q1_bk,   // (2, B, N2)
    float* __restrict__ pb, int t, int store_w)
{
    const int kt = blockIdx.x >> 7;         // 0..7
    const int chunk = blockIdx.x & 127;     // 0..127
    const int k0 = kt * 256 + threadIdx.x;
    const int j0 = chunk * 32;
    const int cur = t & 1, prev = 1 - cur;

    float acc0[B_];
    #pragma unroll
    for (int b = 0; b < B_; ++b) acc0[b] = 0.f;

    const float* s1c = s1_jb + (size_t)cur * N1_ * B_;

    if (t > 0) {
        float s2v0[B_], q1v0[B_];
        #pragma unroll
        for (int b = 0; b < B_; ++b) {
            s2v0[b] = s2_bk[((size_t)prev * B_ + b) * N2_ + k0];
            q1v0[b] = q1_bk[((size_t)prev * B_ + b) * N2_ + k0];
        }
        const float* p1p = p1_jb + (size_t)prev * N1_ * B_;
        const float* s1p = s1_jb + (size_t)prev * N1_ * B_;
        float w0 = Wb[(size_t)j0 * N2_ + k0];
        #pragma unroll 2
        for (int jj = j0; jj < j0 + 32; ++jj) {
            const int jp = (jj < j0 + 31) ? (jj + 1) : jj;  // prefetch next row's weight
            float w0n = Wb[(size_t)jp * N2_ + k0];
            float4 p1r[4], s1pr[4], s1cr[4];
            ld_row4(p1r,  p1p + (size_t)jj * B_);
            ld_row4(s1pr, s1p + (size_t)jj * B_);
            ld_row4(s1cr, s1c + (size_t)jj * B_);
            float t1a = dot16(p1r, s2v0), t2a = dot16(s1pr, q1v0);
            float wn0 = __fadd_rn(w0, __fmul_rn(0.01f, __fsub_rn(t1a, t2a)));
            wn0 = fminf(fmaxf(wn0, -1.0f), 1.0f);
            if (store_w)
                Wb[(size_t)jj * N2_ + k0] = wn0;
            acc16(acc0, s1cr, wn0);
            w0 = w0n;
        }
    } else {
        #pragma unroll 2
        for (int jj = j0; jj < j0 + 32; ++jj) {
            float4 s1cr[4];
            ld_row4(s1cr, s1c + (size_t)jj * B_);
            float w0 = Wb[(size_t)jj * N2_ + k0];
            acc16(acc0, s1cr, w0);
        }
    }
    #pragma unroll
    for (int b = 0; b < B_; ++b)
        pb[((size_t)chunk * B_ + b) * N2_ + k0] = acc0[b];
}

// ---- standalone lif2 (used once, for t = T-1) — exact R1 body ----
__global__ __launch_bounds__(256) void lif2_kernel(
    const float* __restrict__ pb, float* __restrict__ V2, float* __restrict__ r2,
    float* __restrict__ s2_bk, float* __restrict__ q1_bk,
    float* __restrict__ counts, int t)
{
    int tid = blockIdx.x * 256 + threadIdx.x;      // 32768 = B*N2
    int b = tid >> 11, k = tid & (N2_ - 1);
    float y = 0.f;
    #pragma unroll 16
    for (int c = 0; c < 128; ++c) y += pb[((size_t)c * B_ + b) * N2_ + k];
    float V = __fadd_rn(__fmul_rn(0.9f, V2[tid]), y);
    float rr = r2[tid];
    bool spk = (V > 1.0f) && (rr <= 0.0f);
    float s = spk ? 1.0f : 0.0f;
    V2[tid] = spk ? 0.0f : V;
    r2[tid] = spk ? 2.0f : fmaxf(rr - 1.0f, 0.0f);
    int cur = t & 1, prev = 1 - cur;
    s2_bk[(size_t)cur * B_ * N2_ + tid] = s;
    float q1 = __fadd_rn(__fmul_rn(0.95f, q1_bk[(size_t)prev * B_ * N2_ + tid]), s);
    q1_bk[(size_t)cur * B_ * N2_ + tid] = q1;
    counts[tid] = counts[tid] + s;
}

// ---- decode: out = counts @ W_dec + b_dec ----
__global__ __launch_bounds__(256) void decode_kernel(
    const float* __restrict__ counts, const float* __restrict__ W_dec,
    const float* __restrict__ b_dec, float* __restrict__ out)
{
    int tid = threadIdx.x;
    if (tid < B_ * NC_) {
        int b = tid / NC_, c = tid % NC_;
        float a = 0.f;
        for (int k = 0; k < N2_; ++k)
            a = fmaf(counts[(size_t)b * N2_ + k], W_dec[(size_t)k * NC_ + c], a);
        out[tid] = __fadd_rn(a, b_dec[c]);
    }
}

extern "C" void kernel_launch(void* const* d_in, const int* in_sizes, int n_in,
                              void* d_out, int out_size, void* d_ws, size_t ws_size,
                              hipStream_t stream) {
    const float* x     = (const float*)d_in[0];
    const float* u     = (const float*)d_in[1];
    const float* W_enc = (const float*)d_in[2];
    const float* b_enc = (const float*)d_in[3];
    float* Wa          = (float*)d_in[4];   // updated in place; harness restores before every timed launch
    float* Wb          = (float*)d_in[5];
    const float* W_dec = (const float*)d_in[6];
    const float* b_dec = (const float*)d_in[7];
    float* out         = (float*)d_out;

    float* ws = (float*)d_ws;
    size_t off = 0;
    float* rates  = ws + off; off += (size_t)B_ * N0_;
    float* s0_all = ws + off; off += (size_t)T_ * N0_ * B_;
    float* p0_all = ws + off; off += (size_t)T_ * N0_ * B_;
    float* s1_bj  = ws + off; off += 2 * (size_t)B_ * N1_;
    float* s1_jb  = ws + off; off += 2 * (size_t)B_ * N1_;
    float* pa     = ws + off; off += 64 * (size_t)B_ * N1_;
    float* pb     = ws + off; off += 128 * (size_t)B_ * N2_;
    float* zblock = ws + off;                       // everything below is zero-init state
    float* q0_bj  = ws + off; off += 2 * (size_t)B_ * N1_;
    float* p1_jb  = ws + off; off += 2 * (size_t)B_ * N1_;
    float* q1_bk  = ws + off; off += 2 * (size_t)B_ * N2_;
    float* s2_bk  = ws + off; off += 2 * (size_t)B_ * N2_;
    float* V1     = ws + off; off += (size_t)B_ * N1_;
    float* r1     = ws + off; off += (size_t)B_ * N1_;
    float* V2     = ws + off; off += (size_t)B_ * N2_;
    float* r2     = ws + off; off += (size_t)B_ * N2_;
    float* counts = ws + off; off += (size_t)B_ * N2_;
    size_t zbytes = (size_t)((ws + off) - zblock) * sizeof(float);

    hipMemsetAsync(zblock, 0, zbytes, stream);
    rates_kernel<<<256, 256, 0, stream>>>(x, W_enc, b_enc, rates);
    layer0_kernel<<<256, 256, 0, stream>>>(u, rates, s0_all, p0_all);
    for (int t = 0; t < T_; ++t) {
        int store_w = (t < T_ - 1) ? 1 : 0;
        // K1: ka(t) + lif2(t-1) fused by block-range (independent data)
        ka_lif2_kernel<<<1152, 256, 0, stream>>>(Wa, s0_all, p0_all, s1_bj, q0_bj, pa,
                                                 pb, V2, r2, s2_bk, q1_bk, counts,
                                                 t, store_w);
        lif1_kernel<<<256, 256, 0, stream>>>(pa, V1, r1, s1_bj, s1_jb, q0_bj, p1_jb, t);
        kb_kernel<<<1024, 256, 0, stream>>>(Wb, s1_jb, p1_jb, s2_bk, q1_bk, pb, t, store_w);
    }
    lif2_kernel<<<128, 256, 0, stream>>>(pb, V2, r2, s2_bk, q1_bk, counts, T_ - 1);
    decode_kernel<<<1, 256, 0, stream>>>(counts, W_dec, b_dec, out);
}